// Round 16
// baseline (944.593 us; speedup 1.0000x reference)
//
#include <hip/hip_runtime.h>
#include <math.h>

// Problem constants (fixed by the reference).
#define NN   100000
#define EE   1600000
#define F    128      // IN_FEATS == H == 128
#define ZD   32       // Z_DIM
#define SCAN_B 256
#define PREP_BLOCKS 161
#define FC1_BLOCKS  1563   // ceil(100000/64)
#define ENC_BLOCKS  1563
#define NBUCK 391          // ceil(100000/256) dst-range buckets
#define PART_CHUNK 2048
#define PART_BLOCKS 782    // ceil(1600000/2048)

// Algebra (scaled-propagation form; D = diag(dinv)):
//  P(X)~ = X~ - D^2 (sum_e X~[src]);  encoder via 32-wide, decoder via 128-wide
//  gathers in scaled space (no per-edge dinv). CSR padded to 16 (pad idx = n,
//  zero row) -> unconditional 16-deep gather batches; direct (uniform-address)
//  index loads, no shuffles.
//  R15 change: edge partition uses ONE global atomicAdd per edge on the 391
//  L2-hot bucket cursors (replaces the hist/reserve/lofs LDS-atomic pipeline
//  and its 367K bank conflicts).
//  out = vgae_loss = sum((x_rec-feats)^2) - 0.5*sum(1+mu-mu^2-exp(mu))

typedef float f32x4 __attribute__((ext_vector_type(4)));
typedef int   i32x4 __attribute__((ext_vector_type(4)));
typedef __bf16 bf16x8 __attribute__((ext_vector_type(8)));

__device__ __forceinline__ f32x4 mfma16(i32x4 a, i32x4 b, f32x4 c) {
    return __builtin_amdgcn_mfma_f32_16x16x32_bf16(
        __builtin_bit_cast(bf16x8, a), __builtin_bit_cast(bf16x8, b), c, 0, 0, 0);
}

__device__ __forceinline__ unsigned f2bf(float f) {   // RNE float->bf16 (as u16)
    unsigned u = __float_as_uint(f);
    return (u + 0x7fffu + ((u >> 16) & 1u)) >> 16;
}
__device__ __forceinline__ float bf2f(unsigned h) { return __uint_as_float(h << 16); }

__device__ __forceinline__ unsigned pcg_hash(unsigned v) {
    v = v * 747796405u + 2891336453u;
    unsigned w = ((v >> ((v >> 28u) + 4u)) ^ v) * 277803737u;
    return (w >> 22u) ^ w;
}

__device__ __forceinline__ float block_reduce_sum(float v) {
    #pragma unroll
    for (int o = 32; o > 0; o >>= 1) v += __shfl_down(v, o, 64);
    __shared__ float s[8];
    int lane = threadIdx.x & 63, w = threadIdx.x >> 6;
    if (lane == 0) s[w] = v;
    __syncthreads();
    float t = 0.f;
    if (threadIdx.x == 0) {
        int nw = (blockDim.x + 63) >> 6;
        for (int i = 0; i < nw; ++i) t += s[i];
    }
    return t;
}

// ---------- fused: weight prep (blocks 0..160) || bucket count (rest) ----------
__global__ __launch_bounds__(256) void prep_bcnt_kernel(
        const float* __restrict__ repw, const float* __restrict__ w2e,
        const float* __restrict__ b2e,  const float* __restrict__ repb,
        const float* __restrict__ w2d,
        const float* __restrict__ w1d,  const float* __restrict__ recw,
        const float* __restrict__ recb, const float* __restrict__ b1d,
        const float* __restrict__ w1e,
        unsigned short* __restrict__ Wcat,   // 96 x 128
        float* __restrict__ bmu,             // 32
        unsigned short* __restrict__ wd2_a,  // 128 x 128
        unsigned short* __restrict__ wd2_b,
        unsigned short* __restrict__ wd2_c,
        unsigned short* __restrict__ wrd,    // 128 x 32
        float* __restrict__ brd,             // 128
        unsigned short* __restrict__ w1bf,   // 128 x 128
        const int* __restrict__ dst, int* __restrict__ bcnt, int e) {
    int bid = blockIdx.x, tid = threadIdx.x;
    if (bid >= PREP_BLOCKS) {             // bucket count (LDS hist -> 391 atomics)
        __shared__ int hist[NBUCK];
        int pid = bid - PREP_BLOCKS;
        int e0 = pid * PART_CHUNK;
        int e1 = min(e0 + PART_CHUNK, e);
        for (int bb = tid; bb < NBUCK; bb += 256) hist[bb] = 0;
        __syncthreads();
        for (int i = e0 + tid; i < e1; i += 256) atomicAdd(&hist[dst[i] >> 8], 1);
        __syncthreads();
        for (int bb = tid; bb < NBUCK; bb += 256)
            if (hist[bb]) atomicAdd(&bcnt[bb], hist[bb]);
        return;
    }
    if (bid < 16) {                       // Wcat: 32*128 entries
        int idx = bid * 256 + tid;
        int i = idx >> 7, k = idx & 127;
        float m0 = 0.f, m1 = 0.f, m2 = 0.f;
        for (int h = 0; h < 128; ++h) {
            float r = repw[i * 128 + h];
            const float* wr = w2e + (size_t)h * 384 + k;
            m0 += r * wr[0];
            m1 += r * wr[128];
            m2 += r * wr[256];
        }
        Wcat[(size_t)i * 128 + k]        = (unsigned short)f2bf(3.f * m0);
        Wcat[(size_t)(32 + i) * 128 + k] = (unsigned short)f2bf(3.f * (m1 - m0));
        Wcat[(size_t)(64 + i) * 128 + k] = (unsigned short)f2bf(0.75f * m0 - 1.5f * m1 + 0.75f * m2);
    } else if (bid == 16) {               // bmu
        if (tid < 32) {
            float s = repb[tid];
            for (int h = 0; h < 128; ++h) s += repw[tid * 128 + h] * b2e[h];
            bmu[tid] = s;
        }
    } else if (bid < 81) {                // wd2: 128*128
        int idx = (bid - 17) * 256 + tid;
        int j = idx >> 7, k = idx & 127;
        const float* wr = w2d + (size_t)j * 384 + k;
        float w0 = wr[0], w1 = wr[128], w2v = wr[256];
        wd2_a[idx] = (unsigned short)f2bf(3.f * w0);
        wd2_b[idx] = (unsigned short)f2bf(3.f * (w1 - w0));
        wd2_c[idx] = (unsigned short)f2bf(0.75f * w0 - 1.5f * w1 + 0.75f * w2v);
    } else if (bid < 97) {                // wrd: 128*32 (+brd)
        int idx = (bid - 81) * 256 + tid;
        int j = idx >> 5, i = idx & 31;
        float s = 0.f;
        for (int h = 0; h < 128; ++h) s += w1d[j * 128 + h] * recw[h * 32 + i];
        wrd[idx] = (unsigned short)f2bf(s);
        if (idx < 128) {
            float b = b1d[idx];
            for (int h = 0; h < 128; ++h) b += w1d[idx * 128 + h] * recb[h];
            brd[idx] = b;
        }
    } else {                              // w1 convert: 128*128
        int idx = (bid - 97) * 256 + tid;
        w1bf[idx] = (unsigned short)f2bf(w1e[idx]);
    }
}

// ---------- scan 391 bucket counts -> bstart2 (exact ebuf coords) ----------
__global__ __launch_bounds__(512) void bscan_kernel(const int* __restrict__ bcnt,
                                                    int* __restrict__ bstart2,
                                                    int* __restrict__ bcursor2, int e) {
    __shared__ int sh[512];
    int tid = threadIdx.x;
    int v = (tid < NBUCK) ? bcnt[tid] : 0;
    sh[tid] = v;
    __syncthreads();
    for (int o = 1; o < 512; o <<= 1) {
        int t = (tid >= o) ? sh[tid - o] : 0;
        __syncthreads();
        sh[tid] += t;
        __syncthreads();
    }
    if (tid < NBUCK) {
        int s = sh[tid] - v;   // exclusive
        bstart2[tid] = s;
        bcursor2[tid] = s;
    }
    if (tid == 0) bstart2[NBUCK] = e;
}

// ---------- per-bucket degree count from partitioned ebuf (LDS counters) ----------
__global__ __launch_bounds__(256) void degcnt_kernel(const int* __restrict__ ebuf,
                                                     const int* __restrict__ bstart2,
                                                     int* __restrict__ degs, int n) {
    __shared__ int cnt[256];
    int tid = threadIdx.x;
    int bb = blockIdx.x;
    cnt[tid] = 0;
    __syncthreads();
    int s0 = bstart2[bb], s1 = bstart2[bb + 1];
    for (int i = s0 + tid; i < s1; i += 256) atomicAdd(&cnt[ebuf[i] & 255], 1);
    __syncthreads();
    int node = bb * 256 + tid;
    if (node < n) degs[node] = cnt[tid];
}

// ---------- two-level exclusive scan over PADDED degs -> rowstart ----------
__global__ __launch_bounds__(SCAN_B) void scan_block_kernel(const int* __restrict__ degs,
                                                            int* __restrict__ rowstart,
                                                            int* __restrict__ blocksums,
                                                            float* __restrict__ dinv,
                                                            float* __restrict__ rsq, int n) {
    __shared__ int sh[SCAN_B];
    int i = blockIdx.x * SCAN_B + threadIdx.x;
    int v = (i < n) ? degs[i] : 0;
    int pd = (v + 15) & ~15;
    sh[threadIdx.x] = pd;
    __syncthreads();
    for (int o = 1; o < SCAN_B; o <<= 1) {
        int t = (threadIdx.x >= o) ? sh[threadIdx.x - o] : 0;
        __syncthreads();
        sh[threadIdx.x] += t;
        __syncthreads();
    }
    if (i < n) {
        rowstart[i] = sh[threadIdx.x] - pd;
        float d = fmaxf((float)v, 1.f);
        float s = sqrtf(d);
        rsq[i] = s;
        dinv[i] = 1.f / s;
    }
    if (threadIdx.x == SCAN_B - 1) blocksums[blockIdx.x] = sh[threadIdx.x];
}

__global__ __launch_bounds__(512) void scan_sums_kernel(int* __restrict__ blocksums, int nb) {
    __shared__ int sh[512];
    int v = (threadIdx.x < nb) ? blocksums[threadIdx.x] : 0;
    sh[threadIdx.x] = v;
    __syncthreads();
    for (int o = 1; o < 512; o <<= 1) {
        int t = (threadIdx.x >= o) ? sh[threadIdx.x - o] : 0;
        __syncthreads();
        sh[threadIdx.x] += t;
        __syncthreads();
    }
    if (threadIdx.x < nb) blocksums[threadIdx.x] = sh[threadIdx.x] - v;
}

// ---------- finalize rowstart; write CSR pads (zero-row idx n) ----------
__global__ __launch_bounds__(SCAN_B) void scan_add_kernel(int* __restrict__ rowstart,
                                                          int* __restrict__ cursor,
                                                          const int* __restrict__ blocksums,
                                                          const int* __restrict__ degs,
                                                          int* __restrict__ csr_src,
                                                          int n) {
    int i = blockIdx.x * SCAN_B + threadIdx.x;
    if (i < n) {
        int v = rowstart[i] + blocksums[blockIdx.x];
        rowstart[i] = v;
        cursor[i] = v;
        int d = degs[i];
        int pd = (d + 15) & ~15;
        for (int j = d; j < pd; ++j) csr_src[v + j] = n;   // pad -> zero row
        if (i == n - 1) rowstart[n] = v + pd;
    }
}

// ---------- fused: fc1 MFMA GEMM || edge partition (global-atomic scatter) ----------
__global__ __launch_bounds__(256) void fc1_part_kernel(const float* __restrict__ x,
                                                       const unsigned short* __restrict__ wbf,
                                                       const float* __restrict__ b,
                                                       unsigned short* __restrict__ out,
                                                       const int* __restrict__ src,
                                                       const int* __restrict__ dst,
                                                       int* __restrict__ bcursor2,
                                                       int* __restrict__ ebuf,
                                                       int n, int e) {
    if (blockIdx.x >= FC1_BLOCKS) {       // partition: 1 global atomic per edge
        int pid = blockIdx.x - FC1_BLOCKS;
        int e0 = pid * PART_CHUNK;
        int e1 = min(e0 + PART_CHUNK, e);
        for (int i = e0 + (int)threadIdx.x; i < e1; i += 256) {
            int d = dst[i];
            int s = src[i];
            int pos = atomicAdd(&bcursor2[d >> 8], 1);   // 391 L2-hot counters
            ebuf[pos] = (s << 8) | (d & 255);
        }
        return;
    }
    int wv = threadIdx.x >> 6, lane = threadIdx.x & 63;
    int l16 = lane & 15, lhi = lane >> 4;
    int rowbase = blockIdx.x * 64 + wv * 16;
    int arow = rowbase + l16;
    f32x4 acc[8];
    #pragma unroll
    for (int jt = 0; jt < 8; ++jt) {
        float bj = b[jt * 16 + l16];
        acc[jt] = (f32x4){bj, bj, bj, bj};
    }
    #pragma unroll
    for (int kk = 0; kk < 4; ++kk) {
        int kbase = kk * 32 + lhi * 8;
        i32x4 afrag = {0, 0, 0, 0};
        if (arow < n) {
            const float* ap = x + (size_t)arow * F + kbase;
            f32x4 f0 = *reinterpret_cast<const f32x4*>(ap);
            f32x4 f1 = *reinterpret_cast<const f32x4*>(ap + 4);
            afrag.x = (int)(f2bf(f0.x) | (f2bf(f0.y) << 16));
            afrag.y = (int)(f2bf(f0.z) | (f2bf(f0.w) << 16));
            afrag.z = (int)(f2bf(f1.x) | (f2bf(f1.y) << 16));
            afrag.w = (int)(f2bf(f1.z) | (f2bf(f1.w) << 16));
        }
        #pragma unroll
        for (int jt = 0; jt < 8; ++jt) {
            i32x4 bfrag = *reinterpret_cast<const i32x4*>(wbf + (size_t)(jt * 16 + l16) * F + kbase);
            acc[jt] = mfma16(afrag, bfrag, acc[jt]);
        }
    }
    #pragma unroll
    for (int jt = 0; jt < 8; ++jt)
        #pragma unroll
        for (int r = 0; r < 4; ++r) {
            int row = rowbase + lhi * 4 + r;
            if (row < n)
                out[(size_t)row * F + jt * 16 + l16] =
                    (unsigned short)f2bf(fmaxf(acc[jt][r], 0.f));
        }
}

// ---------- fused: encoder projection [G0|G~1|G~2] || CSR phase D ----------
__global__ __launch_bounds__(256) void encproj_csr_kernel(const unsigned short* __restrict__ A,
                                                          const unsigned short* __restrict__ Wcat,
                                                          const float* __restrict__ dinv,
                                                          unsigned short* __restrict__ G0,
                                                          unsigned short* __restrict__ G1s,
                                                          unsigned short* __restrict__ G2s,
                                                          const int* __restrict__ ebuf,
                                                          const int* __restrict__ bstart2,
                                                          int* __restrict__ cursor,
                                                          int* __restrict__ csr_src,
                                                          int n) {
    if (blockIdx.x >= ENC_BLOCKS) {       // phase D: within-bucket scatter
        int bb = blockIdx.x - ENC_BLOCKS;
        int s0 = bstart2[bb], s1 = bstart2[bb + 1];
        for (int i = s0 + (int)threadIdx.x; i < s1; i += 256) {
            int p = ebuf[i];
            int d = (bb << 8) | (p & 255);
            int pos = atomicAdd(&cursor[d], 1);
            csr_src[pos] = p >> 8;
        }
        return;
    }
    int wv = threadIdx.x >> 6, lane = threadIdx.x & 63;
    int l16 = lane & 15, lhi = lane >> 4;
    int rowbase = blockIdx.x * 64 + wv * 16;
    int arow = rowbase + l16;
    float dv[4];
    #pragma unroll
    for (int r = 0; r < 4; ++r) {
        int row = rowbase + lhi * 4 + r;
        dv[r] = (row < n) ? dinv[row] : 1.f;
    }
    f32x4 acc[6];
    #pragma unroll
    for (int jt = 0; jt < 6; ++jt) acc[jt] = (f32x4){0.f, 0.f, 0.f, 0.f};
    #pragma unroll
    for (int kk = 0; kk < 4; ++kk) {
        int kbase = kk * 32 + lhi * 8;
        i32x4 afrag = {0, 0, 0, 0};
        if (arow < n)
            afrag = *reinterpret_cast<const i32x4*>(A + (size_t)arow * F + kbase);
        #pragma unroll
        for (int jt = 0; jt < 6; ++jt) {
            i32x4 bfrag = *reinterpret_cast<const i32x4*>(Wcat + (size_t)(jt * 16 + l16) * F + kbase);
            acc[jt] = mfma16(afrag, bfrag, acc[jt]);
        }
    }
    #pragma unroll
    for (int jt = 0; jt < 6; ++jt)
        #pragma unroll
        for (int r = 0; r < 4; ++r) {
            int row = rowbase + lhi * 4 + r;
            int j = jt * 16 + l16;
            if (row < n) {
                if (j < 32) {
                    G0[(size_t)row * 32 + j] = (unsigned short)f2bf(acc[jt][r]);
                } else if (j < 64) {
                    G1s[(size_t)row * 32 + (j - 32)] = (unsigned short)f2bf(acc[jt][r] * dv[r]);
                } else {
                    G2s[(size_t)row * 32 + (j - 64)] = (unsigned short)f2bf(acc[jt][r] * dv[r]);
                }
            }
        }
}

// ---------- 32-wide gather: W~ = G~1 + G~2 - dinv^2 * sum(G~2[s]) ----------
__global__ __launch_bounds__(256) void gather32_W_kernel(const unsigned short* __restrict__ G2s,
                                                         const unsigned short* __restrict__ G1s,
                                                         const int* __restrict__ csr_src,
                                                         const int* __restrict__ rowstart,
                                                         const float* __restrict__ dinv,
                                                         unsigned short* __restrict__ W, int n) {
    int g = threadIdx.x >> 4;
    int lane = threadIdx.x & 15;
    int r0 = blockIdx.x * 32 + g * 2;
    if (r0 >= n) return;
    int c = lane * 2;
    int start = rowstart[r0];
    int mid   = rowstart[r0 + 1];
    int end   = rowstart[r0 + 2];
    int pd0 = mid - start;
    int total = end - start;
    float ax0 = 0.f, ay0 = 0.f, ax1 = 0.f, ay1 = 0.f;
    for (int base = 0; base < total; base += 16) {
        const int* ip = csr_src + start + base;
        unsigned v[16];
        #pragma unroll
        for (int q = 0; q < 16; ++q) {
            int sq = ip[q];
            v[q] = *reinterpret_cast<const unsigned*>(G2s + (size_t)sq * 32 + c);
        }
        #pragma unroll
        for (int q = 0; q < 16; ++q) {
            float vx = bf2f(v[q] & 0xffffu), vy = bf2f(v[q] >> 16);
            if (base + q < pd0) { ax0 += vx; ay0 += vy; }
            else                { ax1 += vx; ay1 += vy; }
        }
    }
    {
        float di = dinv[r0], di2 = di * di;
        unsigned g2v = *reinterpret_cast<const unsigned*>(G2s + (size_t)r0 * 32 + c);
        unsigned g1v = *reinterpret_cast<const unsigned*>(G1s + (size_t)r0 * 32 + c);
        float wx = bf2f(g1v & 0xffffu) + bf2f(g2v & 0xffffu) - di2 * ax0;
        float wy = bf2f(g1v >> 16)     + bf2f(g2v >> 16)     - di2 * ay0;
        *reinterpret_cast<unsigned*>(W + (size_t)r0 * 32 + c) = f2bf(wx) | (f2bf(wy) << 16);
    }
    if (r0 + 1 < n) {
        int r1 = r0 + 1;
        float di = dinv[r1], di2 = di * di;
        unsigned g2v = *reinterpret_cast<const unsigned*>(G2s + (size_t)r1 * 32 + c);
        unsigned g1v = *reinterpret_cast<const unsigned*>(G1s + (size_t)r1 * 32 + c);
        float wx = bf2f(g1v & 0xffffu) + bf2f(g2v & 0xffffu) - di2 * ax1;
        float wy = bf2f(g1v >> 16)     + bf2f(g2v >> 16)     - di2 * ay1;
        *reinterpret_cast<unsigned*>(W + (size_t)r1 * 32 + c) = f2bf(wx) | (f2bf(wy) << 16);
    }
}

// ---------- 32-wide gather mu = G0 + rsq*W~ - dinv*sum(W~[s]) + bmu ----------
__global__ __launch_bounds__(256) void gather32_mukl_kernel(const unsigned short* __restrict__ W,
                                                            const unsigned short* __restrict__ G0,
                                                            const int* __restrict__ csr_src,
                                                            const int* __restrict__ rowstart,
                                                            const float* __restrict__ dinv,
                                                            const float* __restrict__ rsq,
                                                            const float* __restrict__ bmu,
                                                            unsigned short* __restrict__ Z,
                                                            double* __restrict__ accd, int n) {
    int g = threadIdx.x >> 4;
    int lane = threadIdx.x & 15;
    int r0 = blockIdx.x * 32 + g * 2;
    int c = lane * 2;
    float kl = 0.f;
    if (r0 < n) {
        int start = rowstart[r0];
        int mid   = rowstart[r0 + 1];
        int end   = rowstart[r0 + 2];
        int pd0 = mid - start;
        int total = end - start;
        float axs0 = 0.f, ays0 = 0.f, axs1 = 0.f, ays1 = 0.f;
        for (int base = 0; base < total; base += 16) {
            const int* ip = csr_src + start + base;
            unsigned v[16];
            #pragma unroll
            for (int q = 0; q < 16; ++q) {
                int sq = ip[q];
                v[q] = *reinterpret_cast<const unsigned*>(W + (size_t)sq * 32 + c);
            }
            #pragma unroll
            for (int q = 0; q < 16; ++q) {
                float vx = bf2f(v[q] & 0xffffu), vy = bf2f(v[q] >> 16);
                if (base + q < pd0) { axs0 += vx; ays0 += vy; }
                else                { axs1 += vx; ays1 += vy; }
            }
        }
        float axs[2] = {axs0, axs1}, ays[2] = {ays0, ays1};
        #pragma unroll
        for (int rr = 0; rr < 2; ++rr) {
            int r = r0 + rr;
            if (r < n) {
                float di = dinv[r];
                float rs = rsq[r];
                unsigned wv = *reinterpret_cast<const unsigned*>(W + (size_t)r * 32 + c);
                unsigned g0v = *reinterpret_cast<const unsigned*>(G0 + (size_t)r * 32 + c);
                float mu0 = bf2f(g0v & 0xffffu) + rs * bf2f(wv & 0xffffu) - di * axs[rr] + bmu[c];
                float mu1 = bf2f(g0v >> 16)     + rs * bf2f(wv >> 16)     - di * ays[rr] + bmu[c + 1];
                kl += (1.f + mu0 - mu0 * mu0 - expf(mu0)) + (1.f + mu1 - mu1 * mu1 - expf(mu1));
                unsigned idx0 = (unsigned)(r * ZD + c);
                unsigned h1 = pcg_hash(2u * idx0 + 1u);
                unsigned h2 = pcg_hash(2u * idx0 + 2u);
                float u1 = ((float)h1 + 0.5f) * 2.3283064365386963e-10f;
                float u2 = ((float)h2 + 0.5f) * 2.3283064365386963e-10f;
                float eps0 = sqrtf(-2.f * logf(u1)) * cosf(6.283185307179586f * u2);
                unsigned idx1 = idx0 + 1u;
                unsigned h3 = pcg_hash(2u * idx1 + 1u);
                unsigned h4 = pcg_hash(2u * idx1 + 2u);
                float u3 = ((float)h3 + 0.5f) * 2.3283064365386963e-10f;
                float u4 = ((float)h4 + 0.5f) * 2.3283064365386963e-10f;
                float eps1 = sqrtf(-2.f * logf(u3)) * cosf(6.283185307179586f * u4);
                float z0 = mu0 + eps0 * expf(0.5f * mu0);
                float z1 = mu1 + eps1 * expf(0.5f * mu1);
                *reinterpret_cast<unsigned*>(Z + (size_t)r * ZD + c) = f2bf(z0) | (f2bf(z1) << 16);
            }
        }
    }
    float bs = block_reduce_sum(kl);
    if (threadIdx.x == 0) atomicAdd(&accd[1], (double)bs);
}

// ---------- 128-wide gather: out = x~ - dinv^2 * sum(x~[s]) ----------
__global__ __launch_bounds__(256) void gather128_kernel(const unsigned short* __restrict__ x,
                                                        const int* __restrict__ csr_src,
                                                        const int* __restrict__ rowstart,
                                                        const float* __restrict__ dinv,
                                                        unsigned short* __restrict__ out, int n) {
    int r = blockIdx.x * 4 + (threadIdx.x >> 6);
    if (r >= n) return;
    int lane = threadIdx.x & 63;
    int c = lane * 2;
    int start = rowstart[r];
    int total = rowstart[r + 1] - start;
    float ax = 0.f, ay = 0.f;
    for (int base = 0; base < total; base += 16) {
        const int* ip = csr_src + start + base;   // wave-uniform
        unsigned v[16];
        #pragma unroll
        for (int q = 0; q < 16; ++q) {
            int sq = ip[q];
            v[q] = *reinterpret_cast<const unsigned*>(x + (size_t)sq * F + c);
        }
        #pragma unroll
        for (int q = 0; q < 16; ++q) {
            ax += bf2f(v[q] & 0xffffu);
            ay += bf2f(v[q] >> 16);
        }
    }
    float di = dinv[r];
    float di2 = di * di;
    unsigned xv = *reinterpret_cast<const unsigned*>(x + (size_t)r * F + c);
    float ox = bf2f(xv & 0xffffu) - di2 * ax;
    float oy = bf2f(xv >> 16) - di2 * ay;
    *reinterpret_cast<unsigned*>(out + (size_t)r * F + c) = f2bf(ox) | (f2bf(oy) << 16);
}

// ---------- recdec1: A~ = dinv * relu(Z @ Wrd^T + brd), K=32 ----------
__global__ __launch_bounds__(256) void recdec1_mfma_kernel(const unsigned short* __restrict__ Z,
                                                           const unsigned short* __restrict__ Wrd,
                                                           const float* __restrict__ brd,
                                                           const float* __restrict__ dinv,
                                                           unsigned short* __restrict__ out, int n) {
    int wv = threadIdx.x >> 6, lane = threadIdx.x & 63;
    int l16 = lane & 15, lhi = lane >> 4;
    int rowbase = blockIdx.x * 64 + wv * 16;
    int arow = rowbase + l16;
    int kbase = lhi * 8;
    float dv[4];
    #pragma unroll
    for (int r = 0; r < 4; ++r) {
        int row = rowbase + lhi * 4 + r;
        dv[r] = (row < n) ? dinv[row] : 1.f;
    }
    i32x4 afrag = {0, 0, 0, 0};
    if (arow < n)
        afrag = *reinterpret_cast<const i32x4*>(Z + (size_t)arow * ZD + kbase);
    #pragma unroll
    for (int jt = 0; jt < 8; ++jt) {
        float bj = brd[jt * 16 + l16];
        f32x4 acc = (f32x4){bj, bj, bj, bj};
        i32x4 bfrag = *reinterpret_cast<const i32x4*>(Wrd + (size_t)(jt * 16 + l16) * ZD + kbase);
        acc = mfma16(afrag, bfrag, acc);
        #pragma unroll
        for (int r = 0; r < 4; ++r) {
            int row = rowbase + lhi * 4 + r;
            if (row < n)
                out[(size_t)row * F + jt * 16 + l16] =
                    (unsigned short)f2bf(fmaxf(acc[r], 0.f) * dv[r]);
        }
    }
}

// ---------- dec2 GEMM (scaled inputs, LDS-staged weights) + loss ----------
__global__ __launch_bounds__(256) void dec2loss_mfma_kernel(const unsigned short* __restrict__ A,
                                                            const unsigned short* __restrict__ B,
                                                            const unsigned short* __restrict__ C,
                                                            const unsigned short* __restrict__ Wa,
                                                            const unsigned short* __restrict__ Wb,
                                                            const unsigned short* __restrict__ Wc,
                                                            const float* __restrict__ b2,
                                                            const float* __restrict__ rsq,
                                                            const float* __restrict__ feats,
                                                            double* __restrict__ accd, int n) {
    __shared__ __align__(16) unsigned short wsh[128 * 128];   // 32 KB, XOR-swizzled
    int tid = threadIdx.x;
    int wv = tid >> 6, lane = tid & 63;
    int l16 = lane & 15, lhi = lane >> 4;
    int rowbase = blockIdx.x * 64 + wv * 16;
    int arow = rowbase + l16;
    float fpre[8][4];
    float rsv[4];
    #pragma unroll
    for (int r = 0; r < 4; ++r) {
        int row = rowbase + lhi * 4 + r;
        rsv[r] = (row < n) ? rsq[row] : 1.f;
    }
    #pragma unroll
    for (int jt = 0; jt < 8; ++jt)
        #pragma unroll
        for (int r = 0; r < 4; ++r) {
            int row = rowbase + lhi * 4 + r;
            fpre[jt][r] = (row < n) ? feats[(size_t)row * F + jt * 16 + l16] : 0.f;
        }
    f32x4 acc[8];
    #pragma unroll
    for (int jt = 0; jt < 8; ++jt) acc[jt] = (f32x4){0.f, 0.f, 0.f, 0.f};
    const unsigned short* mats[3] = {A, B, C};
    const unsigned short* wsrc[3] = {Wa, Wb, Wc};
    #pragma unroll
    for (int s = 0; s < 3; ++s) {
        __syncthreads();
        #pragma unroll
        for (int it = 0; it < 8; ++it) {
            int idx = it * 256 + tid;           // 0..2047
            int j = idx >> 4;
            int colb = (idx & 15) << 4;
            i32x4 v = *reinterpret_cast<const i32x4*>(wsrc[s] + (size_t)j * 128 + ((idx & 15) << 3));
            *reinterpret_cast<i32x4*>((char*)wsh + j * 256 + (colb ^ ((j & 7) << 4))) = v;
        }
        __syncthreads();
        #pragma unroll
        for (int kk = 0; kk < 4; ++kk) {
            i32x4 afrag = {0, 0, 0, 0};
            if (arow < n)
                afrag = *reinterpret_cast<const i32x4*>(mats[s] + (size_t)arow * F + kk * 32 + lhi * 8);
            #pragma unroll
            for (int jt = 0; jt < 8; ++jt) {
                int j = jt * 16 + l16;
                int colb = (kk * 64 + lhi * 16) ^ ((j & 7) << 4);
                i32x4 bfrag = *reinterpret_cast<const i32x4*>((const char*)wsh + j * 256 + colb);
                acc[jt] = mfma16(afrag, bfrag, acc[jt]);
            }
        }
    }
    float local = 0.f;
    #pragma unroll
    for (int jt = 0; jt < 8; ++jt) {
        float bj = b2[jt * 16 + l16];
        #pragma unroll
        for (int r = 0; r < 4; ++r) {
            int row = rowbase + lhi * 4 + r;
            if (row < n) {
                float d = acc[jt][r] * rsv[r] + bj - fpre[jt][r];
                local += d * d;
            }
        }
    }
    float bs = block_reduce_sum(local);
    if (threadIdx.x == 0) atomicAdd(&accd[0], (double)bs);
}

__global__ void finalize_kernel(const double* __restrict__ acc, float* __restrict__ out) {
    out[0] = (float)(acc[0] - 0.5 * acc[1]);
}

extern "C" void kernel_launch(void* const* d_in, const int* in_sizes, int n_in,
                              void* d_out, int out_size, void* d_ws, size_t ws_size,
                              hipStream_t stream) {
    const float* feats  = (const float*)d_in[0];
    const int*   src    = (const int*)d_in[1];
    const int*   dst    = (const int*)d_in[2];
    const float* enc_w1 = (const float*)d_in[3];
    const float* enc_b1 = (const float*)d_in[4];
    const float* enc_w2 = (const float*)d_in[5];
    const float* enc_b2 = (const float*)d_in[6];
    const float* dec_w1 = (const float*)d_in[7];
    const float* dec_b1 = (const float*)d_in[8];
    const float* dec_w2 = (const float*)d_in[9];
    const float* dec_b2 = (const float*)d_in[10];
    const float* rep_w  = (const float*)d_in[11];
    const float* rep_b  = (const float*)d_in[12];
    const float* rec_w  = (const float*)d_in[13];
    const float* rec_b  = (const float*)d_in[14];
    // d_in[15] = disc_w: unused (dgi branch cancels analytically)

    const int n = NN, e = EE;
    char* ws = (char*)d_ws;
    size_t off = 0;
    auto alloc = [&](size_t bytes) -> void* {
        void* p = ws + off;
        off += (bytes + 255) & ~(size_t)255;
        return p;
    };
    const size_t NFB = (size_t)(n + 1) * F * sizeof(unsigned short);  // +1 zero row
    const size_t N32 = (size_t)(n + 1) * 32 * sizeof(unsigned short);
    const int nScanBlocks = (n + SCAN_B - 1) / SCAN_B;
    const int csrCap = e + 15 * NN + 64;    // padded CSR capacity
    int*    degs    = (int*)alloc((size_t)n * sizeof(int));
    float*  dinv    = (float*)alloc((size_t)n * sizeof(float));
    float*  rsq     = (float*)alloc((size_t)n * sizeof(float));
    int*    rowst   = (int*)alloc((size_t)(n + 1) * sizeof(int));
    int*    cursor  = (int*)alloc((size_t)n * sizeof(int));
    int*    bsums   = (int*)alloc((size_t)nScanBlocks * sizeof(int));
    int*    bcnt    = (int*)alloc(NBUCK * sizeof(int));
    int*    bstart2 = (int*)alloc((NBUCK + 1) * sizeof(int));
    int*    bcursor2= (int*)alloc(NBUCK * sizeof(int));
    int*    ebuf    = (int*)alloc((size_t)e * sizeof(int));        // exact coords
    int*    csr_src = (int*)alloc((size_t)csrCap * sizeof(int));
    unsigned short* Abf = (unsigned short*)alloc(NFB);
    unsigned short* Bbf = (unsigned short*)alloc(NFB);
    unsigned short* Cbf = (unsigned short*)alloc((size_t)n * F * sizeof(unsigned short));
    unsigned short* G0  = (unsigned short*)alloc(N32);
    unsigned short* G1  = (unsigned short*)alloc(N32);
    unsigned short* G2  = (unsigned short*)alloc(N32);
    unsigned short* Wg  = (unsigned short*)alloc(N32);
    unsigned short* Zbf = (unsigned short*)alloc((size_t)n * ZD * sizeof(unsigned short));
    unsigned short* Wcat  = (unsigned short*)alloc(96 * 128 * sizeof(unsigned short));
    unsigned short* w1bf  = (unsigned short*)alloc(128 * 128 * sizeof(unsigned short));
    unsigned short* wd2_a = (unsigned short*)alloc(128 * 128 * sizeof(unsigned short));
    unsigned short* wd2_b = (unsigned short*)alloc(128 * 128 * sizeof(unsigned short));
    unsigned short* wd2_c = (unsigned short*)alloc(128 * 128 * sizeof(unsigned short));
    unsigned short* wrd   = (unsigned short*)alloc(128 * 32 * sizeof(unsigned short));
    float* bmu = (float*)alloc(32 * sizeof(float));
    float* brd = (float*)alloc(128 * sizeof(float));
    double* acc = (double*)alloc(2 * sizeof(double));

    const int gemm64   = (n + 63) / 64;     // 1563
    const int gathBlks = (n + 3) / 4;       // 25000 (128-wide)
    const int g32Blks  = (n + 31) / 32;     // 3125 (2 rows per 16-lane group)

    hipMemsetAsync(bcnt, 0, NBUCK * sizeof(int), stream);
    hipMemsetAsync(acc, 0, 2 * sizeof(double), stream);
    // zero-row (index n) for every gathered matrix
    hipMemsetAsync(Abf + (size_t)n * F, 0, F * sizeof(unsigned short), stream);
    hipMemsetAsync(Bbf + (size_t)n * F, 0, F * sizeof(unsigned short), stream);
    hipMemsetAsync(G2 + (size_t)n * 32, 0, 32 * sizeof(unsigned short), stream);
    hipMemsetAsync(Wg + (size_t)n * 32, 0, 32 * sizeof(unsigned short), stream);

    // weight prep || bucket count (fused; LDS hist, no random atomics)
    prep_bcnt_kernel<<<PREP_BLOCKS + PART_BLOCKS, 256, 0, stream>>>(
        rep_w, enc_w2, enc_b2, rep_b, dec_w2, dec_w1, rec_w, rec_b, dec_b1, enc_w1,
        Wcat, bmu, wd2_a, wd2_b, wd2_c, wrd, brd, w1bf, dst, bcnt, e);

    // bucket scan -> exact ebuf layout
    bscan_kernel<<<1, 512, 0, stream>>>(bcnt, bstart2, bcursor2, e);

    // fc1 GEMM || edge partition phase C (global-atomic scatter)
    fc1_part_kernel<<<FC1_BLOCKS + PART_BLOCKS, 256, 0, stream>>>(
        feats, w1bf, enc_b1, Abf, src, dst, bcursor2, ebuf, n, e);

    // per-bucket degree count from partitioned ebuf (LDS counters)
    degcnt_kernel<<<NBUCK, 256, 0, stream>>>(ebuf, bstart2, degs, n);

    scan_block_kernel<<<nScanBlocks, SCAN_B, 0, stream>>>(degs, rowst, bsums, dinv, rsq, n);
    scan_sums_kernel<<<1, 512, 0, stream>>>(bsums, nScanBlocks);
    scan_add_kernel<<<nScanBlocks, SCAN_B, 0, stream>>>(rowst, cursor, bsums, degs,
                                                        csr_src, n);

    // encoder projection (scaled G1,G2) || CSR phase D (fused; independent)
    encproj_csr_kernel<<<ENC_BLOCKS + NBUCK, 256, 0, stream>>>(
        Abf, Wcat, dinv, G0, G1, G2, ebuf, bstart2, cursor, csr_src, n);

    // encoder gathers (scaled space, padded CSR, direct index loads)
    gather32_W_kernel<<<g32Blks, 256, 0, stream>>>(G2, G1, csr_src, rowst, dinv, Wg, n);
    gather32_mukl_kernel<<<g32Blks, 256, 0, stream>>>(Wg, G0, csr_src, rowst, dinv,
                                                      rsq, bmu, Zbf, acc, n);

    // decoder (scaled space; separate gathers)
    recdec1_mfma_kernel<<<gemm64, 256, 0, stream>>>(Zbf, wrd, brd, dinv, Abf, n);
    gather128_kernel<<<gathBlks, 256, 0, stream>>>(Abf, csr_src, rowst, dinv, Bbf, n);
    gather128_kernel<<<gathBlks, 256, 0, stream>>>(Bbf, csr_src, rowst, dinv, Cbf, n);
    dec2loss_mfma_kernel<<<gemm64, 256, 0, stream>>>(Abf, Bbf, Cbf, wd2_a, wd2_b, wd2_c,
                                                     dec_b2, rsq, feats, acc, n);

    finalize_kernel<<<1, 1, 0, stream>>>(acc, (float*)d_out);
}

// Round 17
// 416.394 us; speedup vs baseline: 2.2685x; 2.2685x over previous
//
#include <hip/hip_runtime.h>
#include <math.h>

// Problem constants (fixed by the reference).
#define NN   100000
#define EE   1600000
#define F    128      // IN_FEATS == H == 128
#define ZD   32       // Z_DIM
#define SCAN_B 256
#define PREP_BLOCKS 161
#define FC1_BLOCKS  1563   // ceil(100000/64)
#define ENC_BLOCKS  1563
#define NBUCK 391          // ceil(100000/256) dst-range buckets
#define PART_CHUNK 2048
#define PART_BLOCKS 782    // ceil(1600000/2048)

// Algebra (scaled-propagation form; D = diag(dinv)):
//  P(X)~ = X~ - D^2 (sum_e X~[src]);  encoder via 32-wide, decoder via 128-wide
//  gathers in scaled space (no per-edge dinv). CSR padded to 16 (pad idx = n,
//  zero row) -> unconditional 16-deep gather batches; direct (uniform-address)
//  index loads, no shuffles.
//  R16 lesson: 1-global-atomic-per-edge partition serializes on 391 hot
//  addresses (~4100 same-address RMWs each) -> 9x slower. REVERTED to the
//  LDS hist/reserve/scatter partition (1 global atomic per chunk-bucket).
//  out = vgae_loss = sum((x_rec-feats)^2) - 0.5*sum(1+mu-mu^2-exp(mu))

typedef float f32x4 __attribute__((ext_vector_type(4)));
typedef int   i32x4 __attribute__((ext_vector_type(4)));
typedef __bf16 bf16x8 __attribute__((ext_vector_type(8)));

__device__ __forceinline__ f32x4 mfma16(i32x4 a, i32x4 b, f32x4 c) {
    return __builtin_amdgcn_mfma_f32_16x16x32_bf16(
        __builtin_bit_cast(bf16x8, a), __builtin_bit_cast(bf16x8, b), c, 0, 0, 0);
}

__device__ __forceinline__ unsigned f2bf(float f) {   // RNE float->bf16 (as u16)
    unsigned u = __float_as_uint(f);
    return (u + 0x7fffu + ((u >> 16) & 1u)) >> 16;
}
__device__ __forceinline__ float bf2f(unsigned h) { return __uint_as_float(h << 16); }

__device__ __forceinline__ unsigned pcg_hash(unsigned v) {
    v = v * 747796405u + 2891336453u;
    unsigned w = ((v >> ((v >> 28u) + 4u)) ^ v) * 277803737u;
    return (w >> 22u) ^ w;
}

__device__ __forceinline__ float block_reduce_sum(float v) {
    #pragma unroll
    for (int o = 32; o > 0; o >>= 1) v += __shfl_down(v, o, 64);
    __shared__ float s[8];
    int lane = threadIdx.x & 63, w = threadIdx.x >> 6;
    if (lane == 0) s[w] = v;
    __syncthreads();
    float t = 0.f;
    if (threadIdx.x == 0) {
        int nw = (blockDim.x + 63) >> 6;
        for (int i = 0; i < nw; ++i) t += s[i];
    }
    return t;
}

// ---------- fused: weight prep (blocks 0..160) || bucket count (rest) ----------
__global__ __launch_bounds__(256) void prep_bcnt_kernel(
        const float* __restrict__ repw, const float* __restrict__ w2e,
        const float* __restrict__ b2e,  const float* __restrict__ repb,
        const float* __restrict__ w2d,
        const float* __restrict__ w1d,  const float* __restrict__ recw,
        const float* __restrict__ recb, const float* __restrict__ b1d,
        const float* __restrict__ w1e,
        unsigned short* __restrict__ Wcat,   // 96 x 128
        float* __restrict__ bmu,             // 32
        unsigned short* __restrict__ wd2_a,  // 128 x 128
        unsigned short* __restrict__ wd2_b,
        unsigned short* __restrict__ wd2_c,
        unsigned short* __restrict__ wrd,    // 128 x 32
        float* __restrict__ brd,             // 128
        unsigned short* __restrict__ w1bf,   // 128 x 128
        const int* __restrict__ dst, int* __restrict__ bcnt, int e) {
    int bid = blockIdx.x, tid = threadIdx.x;
    if (bid >= PREP_BLOCKS) {             // bucket count (LDS hist -> 391 atomics)
        __shared__ int hist[NBUCK];
        int pid = bid - PREP_BLOCKS;
        int e0 = pid * PART_CHUNK;
        int e1 = min(e0 + PART_CHUNK, e);
        for (int bb = tid; bb < NBUCK; bb += 256) hist[bb] = 0;
        __syncthreads();
        for (int i = e0 + tid; i < e1; i += 256) atomicAdd(&hist[dst[i] >> 8], 1);
        __syncthreads();
        for (int bb = tid; bb < NBUCK; bb += 256)
            if (hist[bb]) atomicAdd(&bcnt[bb], hist[bb]);
        return;
    }
    if (bid < 16) {                       // Wcat: 32*128 entries
        int idx = bid * 256 + tid;
        int i = idx >> 7, k = idx & 127;
        float m0 = 0.f, m1 = 0.f, m2 = 0.f;
        for (int h = 0; h < 128; ++h) {
            float r = repw[i * 128 + h];
            const float* wr = w2e + (size_t)h * 384 + k;
            m0 += r * wr[0];
            m1 += r * wr[128];
            m2 += r * wr[256];
        }
        Wcat[(size_t)i * 128 + k]        = (unsigned short)f2bf(3.f * m0);
        Wcat[(size_t)(32 + i) * 128 + k] = (unsigned short)f2bf(3.f * (m1 - m0));
        Wcat[(size_t)(64 + i) * 128 + k] = (unsigned short)f2bf(0.75f * m0 - 1.5f * m1 + 0.75f * m2);
    } else if (bid == 16) {               // bmu
        if (tid < 32) {
            float s = repb[tid];
            for (int h = 0; h < 128; ++h) s += repw[tid * 128 + h] * b2e[h];
            bmu[tid] = s;
        }
    } else if (bid < 81) {                // wd2: 128*128
        int idx = (bid - 17) * 256 + tid;
        int j = idx >> 7, k = idx & 127;
        const float* wr = w2d + (size_t)j * 384 + k;
        float w0 = wr[0], w1 = wr[128], w2v = wr[256];
        wd2_a[idx] = (unsigned short)f2bf(3.f * w0);
        wd2_b[idx] = (unsigned short)f2bf(3.f * (w1 - w0));
        wd2_c[idx] = (unsigned short)f2bf(0.75f * w0 - 1.5f * w1 + 0.75f * w2v);
    } else if (bid < 97) {                // wrd: 128*32 (+brd)
        int idx = (bid - 81) * 256 + tid;
        int j = idx >> 5, i = idx & 31;
        float s = 0.f;
        for (int h = 0; h < 128; ++h) s += w1d[j * 128 + h] * recw[h * 32 + i];
        wrd[idx] = (unsigned short)f2bf(s);
        if (idx < 128) {
            float b = b1d[idx];
            for (int h = 0; h < 128; ++h) b += w1d[idx * 128 + h] * recb[h];
            brd[idx] = b;
        }
    } else {                              // w1 convert: 128*128
        int idx = (bid - 97) * 256 + tid;
        w1bf[idx] = (unsigned short)f2bf(w1e[idx]);
    }
}

// ---------- scan 391 bucket counts -> bstart2 (exact ebuf coords) ----------
__global__ __launch_bounds__(512) void bscan_kernel(const int* __restrict__ bcnt,
                                                    int* __restrict__ bstart2,
                                                    int* __restrict__ bcursor2, int e) {
    __shared__ int sh[512];
    int tid = threadIdx.x;
    int v = (tid < NBUCK) ? bcnt[tid] : 0;
    sh[tid] = v;
    __syncthreads();
    for (int o = 1; o < 512; o <<= 1) {
        int t = (tid >= o) ? sh[tid - o] : 0;
        __syncthreads();
        sh[tid] += t;
        __syncthreads();
    }
    if (tid < NBUCK) {
        int s = sh[tid] - v;   // exclusive
        bstart2[tid] = s;
        bcursor2[tid] = s;
    }
    if (tid == 0) bstart2[NBUCK] = e;
}

// ---------- per-bucket degree count from partitioned ebuf (LDS counters) ----------
__global__ __launch_bounds__(256) void degcnt_kernel(const int* __restrict__ ebuf,
                                                     const int* __restrict__ bstart2,
                                                     int* __restrict__ degs, int n) {
    __shared__ int cnt[256];
    int tid = threadIdx.x;
    int bb = blockIdx.x;
    cnt[tid] = 0;
    __syncthreads();
    int s0 = bstart2[bb], s1 = bstart2[bb + 1];
    for (int i = s0 + tid; i < s1; i += 256) atomicAdd(&cnt[ebuf[i] & 255], 1);
    __syncthreads();
    int node = bb * 256 + tid;
    if (node < n) degs[node] = cnt[tid];
}

// ---------- two-level exclusive scan over PADDED degs -> rowstart ----------
__global__ __launch_bounds__(SCAN_B) void scan_block_kernel(const int* __restrict__ degs,
                                                            int* __restrict__ rowstart,
                                                            int* __restrict__ blocksums,
                                                            float* __restrict__ dinv,
                                                            float* __restrict__ rsq, int n) {
    __shared__ int sh[SCAN_B];
    int i = blockIdx.x * SCAN_B + threadIdx.x;
    int v = (i < n) ? degs[i] : 0;
    int pd = (v + 15) & ~15;
    sh[threadIdx.x] = pd;
    __syncthreads();
    for (int o = 1; o < SCAN_B; o <<= 1) {
        int t = (threadIdx.x >= o) ? sh[threadIdx.x - o] : 0;
        __syncthreads();
        sh[threadIdx.x] += t;
        __syncthreads();
    }
    if (i < n) {
        rowstart[i] = sh[threadIdx.x] - pd;
        float d = fmaxf((float)v, 1.f);
        float s = sqrtf(d);
        rsq[i] = s;
        dinv[i] = 1.f / s;
    }
    if (threadIdx.x == SCAN_B - 1) blocksums[blockIdx.x] = sh[threadIdx.x];
}

__global__ __launch_bounds__(512) void scan_sums_kernel(int* __restrict__ blocksums, int nb) {
    __shared__ int sh[512];
    int v = (threadIdx.x < nb) ? blocksums[threadIdx.x] : 0;
    sh[threadIdx.x] = v;
    __syncthreads();
    for (int o = 1; o < 512; o <<= 1) {
        int t = (threadIdx.x >= o) ? sh[threadIdx.x - o] : 0;
        __syncthreads();
        sh[threadIdx.x] += t;
        __syncthreads();
    }
    if (threadIdx.x < nb) blocksums[threadIdx.x] = sh[threadIdx.x] - v;
}

// ---------- finalize rowstart; write CSR pads (zero-row idx n) ----------
__global__ __launch_bounds__(SCAN_B) void scan_add_kernel(int* __restrict__ rowstart,
                                                          int* __restrict__ cursor,
                                                          const int* __restrict__ blocksums,
                                                          const int* __restrict__ degs,
                                                          int* __restrict__ csr_src,
                                                          int n) {
    int i = blockIdx.x * SCAN_B + threadIdx.x;
    if (i < n) {
        int v = rowstart[i] + blocksums[blockIdx.x];
        rowstart[i] = v;
        cursor[i] = v;
        int d = degs[i];
        int pd = (d + 15) & ~15;
        for (int j = d; j < pd; ++j) csr_src[v + j] = n;   // pad -> zero row
        if (i == n - 1) rowstart[n] = v + pd;
    }
}

// ---------- fused: fc1 MFMA GEMM || edge partition (phase C, LDS pipeline) ----------
__global__ __launch_bounds__(256) void fc1_part_kernel(const float* __restrict__ x,
                                                       const unsigned short* __restrict__ wbf,
                                                       const float* __restrict__ b,
                                                       unsigned short* __restrict__ out,
                                                       const int* __restrict__ src,
                                                       const int* __restrict__ dst,
                                                       int* __restrict__ bcursor2,
                                                       int* __restrict__ ebuf,
                                                       int n, int e) {
    if (blockIdx.x >= FC1_BLOCKS) {       // partition: bucket edges by dst>>8
        __shared__ int hist[NBUCK], lofs[NBUCK], gbase[NBUCK];
        int pid = blockIdx.x - FC1_BLOCKS;
        int e0 = pid * PART_CHUNK;
        int e1 = min(e0 + PART_CHUNK, e);
        int tid = threadIdx.x;
        for (int bb = tid; bb < NBUCK; bb += 256) hist[bb] = 0;
        __syncthreads();
        for (int i = e0 + tid; i < e1; i += 256) atomicAdd(&hist[dst[i] >> 8], 1);
        __syncthreads();
        for (int bb = tid; bb < NBUCK; bb += 256) {
            int cct = hist[bb];
            gbase[bb] = cct ? atomicAdd(&bcursor2[bb], cct) : 0;
            lofs[bb] = 0;
        }
        __syncthreads();
        for (int i = e0 + tid; i < e1; i += 256) {
            int d = dst[i];
            int bb = d >> 8;
            int pos = gbase[bb] + atomicAdd(&lofs[bb], 1);
            ebuf[pos] = (src[i] << 8) | (d & 255);
        }
        return;
    }
    int wv = threadIdx.x >> 6, lane = threadIdx.x & 63;
    int l16 = lane & 15, lhi = lane >> 4;
    int rowbase = blockIdx.x * 64 + wv * 16;
    int arow = rowbase + l16;
    f32x4 acc[8];
    #pragma unroll
    for (int jt = 0; jt < 8; ++jt) {
        float bj = b[jt * 16 + l16];
        acc[jt] = (f32x4){bj, bj, bj, bj};
    }
    #pragma unroll
    for (int kk = 0; kk < 4; ++kk) {
        int kbase = kk * 32 + lhi * 8;
        i32x4 afrag = {0, 0, 0, 0};
        if (arow < n) {
            const float* ap = x + (size_t)arow * F + kbase;
            f32x4 f0 = *reinterpret_cast<const f32x4*>(ap);
            f32x4 f1 = *reinterpret_cast<const f32x4*>(ap + 4);
            afrag.x = (int)(f2bf(f0.x) | (f2bf(f0.y) << 16));
            afrag.y = (int)(f2bf(f0.z) | (f2bf(f0.w) << 16));
            afrag.z = (int)(f2bf(f1.x) | (f2bf(f1.y) << 16));
            afrag.w = (int)(f2bf(f1.z) | (f2bf(f1.w) << 16));
        }
        #pragma unroll
        for (int jt = 0; jt < 8; ++jt) {
            i32x4 bfrag = *reinterpret_cast<const i32x4*>(wbf + (size_t)(jt * 16 + l16) * F + kbase);
            acc[jt] = mfma16(afrag, bfrag, acc[jt]);
        }
    }
    #pragma unroll
    for (int jt = 0; jt < 8; ++jt)
        #pragma unroll
        for (int r = 0; r < 4; ++r) {
            int row = rowbase + lhi * 4 + r;
            if (row < n)
                out[(size_t)row * F + jt * 16 + l16] =
                    (unsigned short)f2bf(fmaxf(acc[jt][r], 0.f));
        }
}

// ---------- fused: encoder projection [G0|G~1|G~2] || CSR phase D ----------
__global__ __launch_bounds__(256) void encproj_csr_kernel(const unsigned short* __restrict__ A,
                                                          const unsigned short* __restrict__ Wcat,
                                                          const float* __restrict__ dinv,
                                                          unsigned short* __restrict__ G0,
                                                          unsigned short* __restrict__ G1s,
                                                          unsigned short* __restrict__ G2s,
                                                          const int* __restrict__ ebuf,
                                                          const int* __restrict__ bstart2,
                                                          int* __restrict__ cursor,
                                                          int* __restrict__ csr_src,
                                                          int n) {
    if (blockIdx.x >= ENC_BLOCKS) {       // phase D: within-bucket scatter
        int bb = blockIdx.x - ENC_BLOCKS;
        int s0 = bstart2[bb], s1 = bstart2[bb + 1];
        for (int i = s0 + (int)threadIdx.x; i < s1; i += 256) {
            int p = ebuf[i];
            int d = (bb << 8) | (p & 255);
            int pos = atomicAdd(&cursor[d], 1);
            csr_src[pos] = p >> 8;
        }
        return;
    }
    int wv = threadIdx.x >> 6, lane = threadIdx.x & 63;
    int l16 = lane & 15, lhi = lane >> 4;
    int rowbase = blockIdx.x * 64 + wv * 16;
    int arow = rowbase + l16;
    float dv[4];
    #pragma unroll
    for (int r = 0; r < 4; ++r) {
        int row = rowbase + lhi * 4 + r;
        dv[r] = (row < n) ? dinv[row] : 1.f;
    }
    f32x4 acc[6];
    #pragma unroll
    for (int jt = 0; jt < 6; ++jt) acc[jt] = (f32x4){0.f, 0.f, 0.f, 0.f};
    #pragma unroll
    for (int kk = 0; kk < 4; ++kk) {
        int kbase = kk * 32 + lhi * 8;
        i32x4 afrag = {0, 0, 0, 0};
        if (arow < n)
            afrag = *reinterpret_cast<const i32x4*>(A + (size_t)arow * F + kbase);
        #pragma unroll
        for (int jt = 0; jt < 6; ++jt) {
            i32x4 bfrag = *reinterpret_cast<const i32x4*>(Wcat + (size_t)(jt * 16 + l16) * F + kbase);
            acc[jt] = mfma16(afrag, bfrag, acc[jt]);
        }
    }
    #pragma unroll
    for (int jt = 0; jt < 6; ++jt)
        #pragma unroll
        for (int r = 0; r < 4; ++r) {
            int row = rowbase + lhi * 4 + r;
            int j = jt * 16 + l16;
            if (row < n) {
                if (j < 32) {
                    G0[(size_t)row * 32 + j] = (unsigned short)f2bf(acc[jt][r]);
                } else if (j < 64) {
                    G1s[(size_t)row * 32 + (j - 32)] = (unsigned short)f2bf(acc[jt][r] * dv[r]);
                } else {
                    G2s[(size_t)row * 32 + (j - 64)] = (unsigned short)f2bf(acc[jt][r] * dv[r]);
                }
            }
        }
}

// ---------- 32-wide gather: W~ = G~1 + G~2 - dinv^2 * sum(G~2[s]) ----------
__global__ __launch_bounds__(256) void gather32_W_kernel(const unsigned short* __restrict__ G2s,
                                                         const unsigned short* __restrict__ G1s,
                                                         const int* __restrict__ csr_src,
                                                         const int* __restrict__ rowstart,
                                                         const float* __restrict__ dinv,
                                                         unsigned short* __restrict__ W, int n) {
    int g = threadIdx.x >> 4;
    int lane = threadIdx.x & 15;
    int r0 = blockIdx.x * 32 + g * 2;
    if (r0 >= n) return;
    int c = lane * 2;
    int start = rowstart[r0];
    int mid   = rowstart[r0 + 1];
    int end   = rowstart[r0 + 2];
    int pd0 = mid - start;
    int total = end - start;
    float ax0 = 0.f, ay0 = 0.f, ax1 = 0.f, ay1 = 0.f;
    for (int base = 0; base < total; base += 16) {
        const int* ip = csr_src + start + base;
        unsigned v[16];
        #pragma unroll
        for (int q = 0; q < 16; ++q) {
            int sq = ip[q];
            v[q] = *reinterpret_cast<const unsigned*>(G2s + (size_t)sq * 32 + c);
        }
        #pragma unroll
        for (int q = 0; q < 16; ++q) {
            float vx = bf2f(v[q] & 0xffffu), vy = bf2f(v[q] >> 16);
            if (base + q < pd0) { ax0 += vx; ay0 += vy; }
            else                { ax1 += vx; ay1 += vy; }
        }
    }
    {
        float di = dinv[r0], di2 = di * di;
        unsigned g2v = *reinterpret_cast<const unsigned*>(G2s + (size_t)r0 * 32 + c);
        unsigned g1v = *reinterpret_cast<const unsigned*>(G1s + (size_t)r0 * 32 + c);
        float wx = bf2f(g1v & 0xffffu) + bf2f(g2v & 0xffffu) - di2 * ax0;
        float wy = bf2f(g1v >> 16)     + bf2f(g2v >> 16)     - di2 * ay0;
        *reinterpret_cast<unsigned*>(W + (size_t)r0 * 32 + c) = f2bf(wx) | (f2bf(wy) << 16);
    }
    if (r0 + 1 < n) {
        int r1 = r0 + 1;
        float di = dinv[r1], di2 = di * di;
        unsigned g2v = *reinterpret_cast<const unsigned*>(G2s + (size_t)r1 * 32 + c);
        unsigned g1v = *reinterpret_cast<const unsigned*>(G1s + (size_t)r1 * 32 + c);
        float wx = bf2f(g1v & 0xffffu) + bf2f(g2v & 0xffffu) - di2 * ax1;
        float wy = bf2f(g1v >> 16)     + bf2f(g2v >> 16)     - di2 * ay1;
        *reinterpret_cast<unsigned*>(W + (size_t)r1 * 32 + c) = f2bf(wx) | (f2bf(wy) << 16);
    }
}

// ---------- 32-wide gather mu = G0 + rsq*W~ - dinv*sum(W~[s]) + bmu ----------
__global__ __launch_bounds__(256) void gather32_mukl_kernel(const unsigned short* __restrict__ W,
                                                            const unsigned short* __restrict__ G0,
                                                            const int* __restrict__ csr_src,
                                                            const int* __restrict__ rowstart,
                                                            const float* __restrict__ dinv,
                                                            const float* __restrict__ rsq,
                                                            const float* __restrict__ bmu,
                                                            unsigned short* __restrict__ Z,
                                                            double* __restrict__ accd, int n) {
    int g = threadIdx.x >> 4;
    int lane = threadIdx.x & 15;
    int r0 = blockIdx.x * 32 + g * 2;
    int c = lane * 2;
    float kl = 0.f;
    if (r0 < n) {
        int start = rowstart[r0];
        int mid   = rowstart[r0 + 1];
        int end   = rowstart[r0 + 2];
        int pd0 = mid - start;
        int total = end - start;
        float axs0 = 0.f, ays0 = 0.f, axs1 = 0.f, ays1 = 0.f;
        for (int base = 0; base < total; base += 16) {
            const int* ip = csr_src + start + base;
            unsigned v[16];
            #pragma unroll
            for (int q = 0; q < 16; ++q) {
                int sq = ip[q];
                v[q] = *reinterpret_cast<const unsigned*>(W + (size_t)sq * 32 + c);
            }
            #pragma unroll
            for (int q = 0; q < 16; ++q) {
                float vx = bf2f(v[q] & 0xffffu), vy = bf2f(v[q] >> 16);
                if (base + q < pd0) { axs0 += vx; ays0 += vy; }
                else                { axs1 += vx; ays1 += vy; }
            }
        }
        float axs[2] = {axs0, axs1}, ays[2] = {ays0, ays1};
        #pragma unroll
        for (int rr = 0; rr < 2; ++rr) {
            int r = r0 + rr;
            if (r < n) {
                float di = dinv[r];
                float rs = rsq[r];
                unsigned wv = *reinterpret_cast<const unsigned*>(W + (size_t)r * 32 + c);
                unsigned g0v = *reinterpret_cast<const unsigned*>(G0 + (size_t)r * 32 + c);
                float mu0 = bf2f(g0v & 0xffffu) + rs * bf2f(wv & 0xffffu) - di * axs[rr] + bmu[c];
                float mu1 = bf2f(g0v >> 16)     + rs * bf2f(wv >> 16)     - di * ays[rr] + bmu[c + 1];
                kl += (1.f + mu0 - mu0 * mu0 - expf(mu0)) + (1.f + mu1 - mu1 * mu1 - expf(mu1));
                unsigned idx0 = (unsigned)(r * ZD + c);
                unsigned h1 = pcg_hash(2u * idx0 + 1u);
                unsigned h2 = pcg_hash(2u * idx0 + 2u);
                float u1 = ((float)h1 + 0.5f) * 2.3283064365386963e-10f;
                float u2 = ((float)h2 + 0.5f) * 2.3283064365386963e-10f;
                float eps0 = sqrtf(-2.f * logf(u1)) * cosf(6.283185307179586f * u2);
                unsigned idx1 = idx0 + 1u;
                unsigned h3 = pcg_hash(2u * idx1 + 1u);
                unsigned h4 = pcg_hash(2u * idx1 + 2u);
                float u3 = ((float)h3 + 0.5f) * 2.3283064365386963e-10f;
                float u4 = ((float)h4 + 0.5f) * 2.3283064365386963e-10f;
                float eps1 = sqrtf(-2.f * logf(u3)) * cosf(6.283185307179586f * u4);
                float z0 = mu0 + eps0 * expf(0.5f * mu0);
                float z1 = mu1 + eps1 * expf(0.5f * mu1);
                *reinterpret_cast<unsigned*>(Z + (size_t)r * ZD + c) = f2bf(z0) | (f2bf(z1) << 16);
            }
        }
    }
    float bs = block_reduce_sum(kl);
    if (threadIdx.x == 0) atomicAdd(&accd[1], (double)bs);
}

// ---------- 128-wide gather: out = x~ - dinv^2 * sum(x~[s]) ----------
__global__ __launch_bounds__(256) void gather128_kernel(const unsigned short* __restrict__ x,
                                                        const int* __restrict__ csr_src,
                                                        const int* __restrict__ rowstart,
                                                        const float* __restrict__ dinv,
                                                        unsigned short* __restrict__ out, int n) {
    int r = blockIdx.x * 4 + (threadIdx.x >> 6);
    if (r >= n) return;
    int lane = threadIdx.x & 63;
    int c = lane * 2;
    int start = rowstart[r];
    int total = rowstart[r + 1] - start;
    float ax = 0.f, ay = 0.f;
    for (int base = 0; base < total; base += 16) {
        const int* ip = csr_src + start + base;   // wave-uniform
        unsigned v[16];
        #pragma unroll
        for (int q = 0; q < 16; ++q) {
            int sq = ip[q];
            v[q] = *reinterpret_cast<const unsigned*>(x + (size_t)sq * F + c);
        }
        #pragma unroll
        for (int q = 0; q < 16; ++q) {
            ax += bf2f(v[q] & 0xffffu);
            ay += bf2f(v[q] >> 16);
        }
    }
    float di = dinv[r];
    float di2 = di * di;
    unsigned xv = *reinterpret_cast<const unsigned*>(x + (size_t)r * F + c);
    float ox = bf2f(xv & 0xffffu) - di2 * ax;
    float oy = bf2f(xv >> 16) - di2 * ay;
    *reinterpret_cast<unsigned*>(out + (size_t)r * F + c) = f2bf(ox) | (f2bf(oy) << 16);
}

// ---------- recdec1: A~ = dinv * relu(Z @ Wrd^T + brd), K=32 ----------
__global__ __launch_bounds__(256) void recdec1_mfma_kernel(const unsigned short* __restrict__ Z,
                                                           const unsigned short* __restrict__ Wrd,
                                                           const float* __restrict__ brd,
                                                           const float* __restrict__ dinv,
                                                           unsigned short* __restrict__ out, int n) {
    int wv = threadIdx.x >> 6, lane = threadIdx.x & 63;
    int l16 = lane & 15, lhi = lane >> 4;
    int rowbase = blockIdx.x * 64 + wv * 16;
    int arow = rowbase + l16;
    int kbase = lhi * 8;
    float dv[4];
    #pragma unroll
    for (int r = 0; r < 4; ++r) {
        int row = rowbase + lhi * 4 + r;
        dv[r] = (row < n) ? dinv[row] : 1.f;
    }
    i32x4 afrag = {0, 0, 0, 0};
    if (arow < n)
        afrag = *reinterpret_cast<const i32x4*>(Z + (size_t)arow * ZD + kbase);
    #pragma unroll
    for (int jt = 0; jt < 8; ++jt) {
        float bj = brd[jt * 16 + l16];
        f32x4 acc = (f32x4){bj, bj, bj, bj};
        i32x4 bfrag = *reinterpret_cast<const i32x4*>(Wrd + (size_t)(jt * 16 + l16) * ZD + kbase);
        acc = mfma16(afrag, bfrag, acc);
        #pragma unroll
        for (int r = 0; r < 4; ++r) {
            int row = rowbase + lhi * 4 + r;
            if (row < n)
                out[(size_t)row * F + jt * 16 + l16] =
                    (unsigned short)f2bf(fmaxf(acc[r], 0.f) * dv[r]);
        }
    }
}

// ---------- dec2 GEMM (scaled inputs, LDS-staged weights) + loss ----------
__global__ __launch_bounds__(256) void dec2loss_mfma_kernel(const unsigned short* __restrict__ A,
                                                            const unsigned short* __restrict__ B,
                                                            const unsigned short* __restrict__ C,
                                                            const unsigned short* __restrict__ Wa,
                                                            const unsigned short* __restrict__ Wb,
                                                            const unsigned short* __restrict__ Wc,
                                                            const float* __restrict__ b2,
                                                            const float* __restrict__ rsq,
                                                            const float* __restrict__ feats,
                                                            double* __restrict__ accd, int n) {
    __shared__ __align__(16) unsigned short wsh[128 * 128];   // 32 KB, XOR-swizzled
    int tid = threadIdx.x;
    int wv = tid >> 6, lane = tid & 63;
    int l16 = lane & 15, lhi = lane >> 4;
    int rowbase = blockIdx.x * 64 + wv * 16;
    int arow = rowbase + l16;
    float fpre[8][4];
    float rsv[4];
    #pragma unroll
    for (int r = 0; r < 4; ++r) {
        int row = rowbase + lhi * 4 + r;
        rsv[r] = (row < n) ? rsq[row] : 1.f;
    }
    #pragma unroll
    for (int jt = 0; jt < 8; ++jt)
        #pragma unroll
        for (int r = 0; r < 4; ++r) {
            int row = rowbase + lhi * 4 + r;
            fpre[jt][r] = (row < n) ? feats[(size_t)row * F + jt * 16 + l16] : 0.f;
        }
    f32x4 acc[8];
    #pragma unroll
    for (int jt = 0; jt < 8; ++jt) acc[jt] = (f32x4){0.f, 0.f, 0.f, 0.f};
    const unsigned short* mats[3] = {A, B, C};
    const unsigned short* wsrc[3] = {Wa, Wb, Wc};
    #pragma unroll
    for (int s = 0; s < 3; ++s) {
        __syncthreads();
        #pragma unroll
        for (int it = 0; it < 8; ++it) {
            int idx = it * 256 + tid;           // 0..2047
            int j = idx >> 4;
            int colb = (idx & 15) << 4;
            i32x4 v = *reinterpret_cast<const i32x4*>(wsrc[s] + (size_t)j * 128 + ((idx & 15) << 3));
            *reinterpret_cast<i32x4*>((char*)wsh + j * 256 + (colb ^ ((j & 7) << 4))) = v;
        }
        __syncthreads();
        #pragma unroll
        for (int kk = 0; kk < 4; ++kk) {
            i32x4 afrag = {0, 0, 0, 0};
            if (arow < n)
                afrag = *reinterpret_cast<const i32x4*>(mats[s] + (size_t)arow * F + kk * 32 + lhi * 8);
            #pragma unroll
            for (int jt = 0; jt < 8; ++jt) {
                int j = jt * 16 + l16;
                int colb = (kk * 64 + lhi * 16) ^ ((j & 7) << 4);
                i32x4 bfrag = *reinterpret_cast<const i32x4*>((const char*)wsh + j * 256 + colb);
                acc[jt] = mfma16(afrag, bfrag, acc[jt]);
            }
        }
    }
    float local = 0.f;
    #pragma unroll
    for (int jt = 0; jt < 8; ++jt) {
        float bj = b2[jt * 16 + l16];
        #pragma unroll
        for (int r = 0; r < 4; ++r) {
            int row = rowbase + lhi * 4 + r;
            if (row < n) {
                float d = acc[jt][r] * rsv[r] + bj - fpre[jt][r];
                local += d * d;
            }
        }
    }
    float bs = block_reduce_sum(local);
    if (threadIdx.x == 0) atomicAdd(&accd[0], (double)bs);
}

__global__ void finalize_kernel(const double* __restrict__ acc, float* __restrict__ out) {
    out[0] = (float)(acc[0] - 0.5 * acc[1]);
}

extern "C" void kernel_launch(void* const* d_in, const int* in_sizes, int n_in,
                              void* d_out, int out_size, void* d_ws, size_t ws_size,
                              hipStream_t stream) {
    const float* feats  = (const float*)d_in[0];
    const int*   src    = (const int*)d_in[1];
    const int*   dst    = (const int*)d_in[2];
    const float* enc_w1 = (const float*)d_in[3];
    const float* enc_b1 = (const float*)d_in[4];
    const float* enc_w2 = (const float*)d_in[5];
    const float* enc_b2 = (const float*)d_in[6];
    const float* dec_w1 = (const float*)d_in[7];
    const float* dec_b1 = (const float*)d_in[8];
    const float* dec_w2 = (const float*)d_in[9];
    const float* dec_b2 = (const float*)d_in[10];
    const float* rep_w  = (const float*)d_in[11];
    const float* rep_b  = (const float*)d_in[12];
    const float* rec_w  = (const float*)d_in[13];
    const float* rec_b  = (const float*)d_in[14];
    // d_in[15] = disc_w: unused (dgi branch cancels analytically)

    const int n = NN, e = EE;
    char* ws = (char*)d_ws;
    size_t off = 0;
    auto alloc = [&](size_t bytes) -> void* {
        void* p = ws + off;
        off += (bytes + 255) & ~(size_t)255;
        return p;
    };
    const size_t NFB = (size_t)(n + 1) * F * sizeof(unsigned short);  // +1 zero row
    const size_t N32 = (size_t)(n + 1) * 32 * sizeof(unsigned short);
    const int nScanBlocks = (n + SCAN_B - 1) / SCAN_B;
    const int csrCap = e + 15 * NN + 64;    // padded CSR capacity
    int*    degs    = (int*)alloc((size_t)n * sizeof(int));
    float*  dinv    = (float*)alloc((size_t)n * sizeof(float));
    float*  rsq     = (float*)alloc((size_t)n * sizeof(float));
    int*    rowst   = (int*)alloc((size_t)(n + 1) * sizeof(int));
    int*    cursor  = (int*)alloc((size_t)n * sizeof(int));
    int*    bsums   = (int*)alloc((size_t)nScanBlocks * sizeof(int));
    int*    bcnt    = (int*)alloc(NBUCK * sizeof(int));
    int*    bstart2 = (int*)alloc((NBUCK + 1) * sizeof(int));
    int*    bcursor2= (int*)alloc(NBUCK * sizeof(int));
    int*    ebuf    = (int*)alloc((size_t)e * sizeof(int));        // exact coords
    int*    csr_src = (int*)alloc((size_t)csrCap * sizeof(int));
    unsigned short* Abf = (unsigned short*)alloc(NFB);
    unsigned short* Bbf = (unsigned short*)alloc(NFB);
    unsigned short* Cbf = (unsigned short*)alloc((size_t)n * F * sizeof(unsigned short));
    unsigned short* G0  = (unsigned short*)alloc(N32);
    unsigned short* G1  = (unsigned short*)alloc(N32);
    unsigned short* G2  = (unsigned short*)alloc(N32);
    unsigned short* Wg  = (unsigned short*)alloc(N32);
    unsigned short* Zbf = (unsigned short*)alloc((size_t)n * ZD * sizeof(unsigned short));
    unsigned short* Wcat  = (unsigned short*)alloc(96 * 128 * sizeof(unsigned short));
    unsigned short* w1bf  = (unsigned short*)alloc(128 * 128 * sizeof(unsigned short));
    unsigned short* wd2_a = (unsigned short*)alloc(128 * 128 * sizeof(unsigned short));
    unsigned short* wd2_b = (unsigned short*)alloc(128 * 128 * sizeof(unsigned short));
    unsigned short* wd2_c = (unsigned short*)alloc(128 * 128 * sizeof(unsigned short));
    unsigned short* wrd   = (unsigned short*)alloc(128 * 32 * sizeof(unsigned short));
    float* bmu = (float*)alloc(32 * sizeof(float));
    float* brd = (float*)alloc(128 * sizeof(float));
    double* acc = (double*)alloc(2 * sizeof(double));

    const int gemm64   = (n + 63) / 64;     // 1563
    const int gathBlks = (n + 3) / 4;       // 25000 (128-wide)
    const int g32Blks  = (n + 31) / 32;     // 3125 (2 rows per 16-lane group)

    hipMemsetAsync(bcnt, 0, NBUCK * sizeof(int), stream);
    hipMemsetAsync(acc, 0, 2 * sizeof(double), stream);
    // zero-row (index n) for every gathered matrix
    hipMemsetAsync(Abf + (size_t)n * F, 0, F * sizeof(unsigned short), stream);
    hipMemsetAsync(Bbf + (size_t)n * F, 0, F * sizeof(unsigned short), stream);
    hipMemsetAsync(G2 + (size_t)n * 32, 0, 32 * sizeof(unsigned short), stream);
    hipMemsetAsync(Wg + (size_t)n * 32, 0, 32 * sizeof(unsigned short), stream);

    // weight prep || bucket count (fused; LDS hist, no random atomics)
    prep_bcnt_kernel<<<PREP_BLOCKS + PART_BLOCKS, 256, 0, stream>>>(
        rep_w, enc_w2, enc_b2, rep_b, dec_w2, dec_w1, rec_w, rec_b, dec_b1, enc_w1,
        Wcat, bmu, wd2_a, wd2_b, wd2_c, wrd, brd, w1bf, dst, bcnt, e);

    // bucket scan -> exact ebuf layout
    bscan_kernel<<<1, 512, 0, stream>>>(bcnt, bstart2, bcursor2, e);

    // fc1 GEMM || edge partition phase C (LDS hist/reserve/scatter)
    fc1_part_kernel<<<FC1_BLOCKS + PART_BLOCKS, 256, 0, stream>>>(
        feats, w1bf, enc_b1, Abf, src, dst, bcursor2, ebuf, n, e);

    // per-bucket degree count from partitioned ebuf (LDS counters)
    degcnt_kernel<<<NBUCK, 256, 0, stream>>>(ebuf, bstart2, degs, n);

    scan_block_kernel<<<nScanBlocks, SCAN_B, 0, stream>>>(degs, rowst, bsums, dinv, rsq, n);
    scan_sums_kernel<<<1, 512, 0, stream>>>(bsums, nScanBlocks);
    scan_add_kernel<<<nScanBlocks, SCAN_B, 0, stream>>>(rowst, cursor, bsums, degs,
                                                        csr_src, n);

    // encoder projection (scaled G1,G2) || CSR phase D (fused; independent)
    encproj_csr_kernel<<<ENC_BLOCKS + NBUCK, 256, 0, stream>>>(
        Abf, Wcat, dinv, G0, G1, G2, ebuf, bstart2, cursor, csr_src, n);

    // encoder gathers (scaled space, padded CSR, direct index loads)
    gather32_W_kernel<<<g32Blks, 256, 0, stream>>>(G2, G1, csr_src, rowst, dinv, Wg, n);
    gather32_mukl_kernel<<<g32Blks, 256, 0, stream>>>(Wg, G0, csr_src, rowst, dinv,
                                                      rsq, bmu, Zbf, acc, n);

    // decoder (scaled space; separate gathers)
    recdec1_mfma_kernel<<<gemm64, 256, 0, stream>>>(Zbf, wrd, brd, dinv, Abf, n);
    gather128_kernel<<<gathBlks, 256, 0, stream>>>(Abf, csr_src, rowst, dinv, Bbf, n);
    gather128_kernel<<<gathBlks, 256, 0, stream>>>(Bbf, csr_src, rowst, dinv, Cbf, n);
    dec2loss_mfma_kernel<<<gemm64, 256, 0, stream>>>(Abf, Bbf, Cbf, wd2_a, wd2_b, wd2_c,
                                                     dec_b2, rsq, feats, acc, n);

    finalize_kernel<<<1, 1, 0, stream>>>(acc, (float*)d_out);
}